// Round 1
// baseline (381.655 us; speedup 1.0000x reference)
//
#include <hip/hip_runtime.h>
#include <cmath>

// Problem constants (from reference)
#define NB 4
#define NP 8192          // 2^13 points per batch
#define NE 262144        // 2^18 edges per batch
#define NCIN 32
#define NCOUT 32
#define NH 16
#define GAMMA 4.0f
#define NBUCKET (NB * NP)        // 32768 destination buckets (b*8192 + dst)
#define NEDGES_TOT (NB * NE)     // 1048576 edges total

typedef _Float16 half8 __attribute__((ext_vector_type(8)));
typedef float floatx4 __attribute__((ext_vector_type(4)));

// ---------------------------------------------------------------------------
// Phase 1: histogram of destination buckets (cnt must be pre-zeroed)
// ---------------------------------------------------------------------------
__global__ __launch_bounds__(256)
void hist_kernel(const int* __restrict__ edge_dst, int* __restrict__ cnt)
{
    const long stride = (long)gridDim.x * blockDim.x;
    for (long e = (long)blockIdx.x * blockDim.x + threadIdx.x; e < NEDGES_TOT; e += stride) {
        const int b = (int)(e >> 18);                 // NE = 2^18
        atomicAdd(&cnt[(b << 13) | edge_dst[e]], 1);
    }
}

// ---------------------------------------------------------------------------
// Phase 2: exclusive prefix sum over 32768 buckets. One block of 1024 threads,
// each thread owns 32 consecutive buckets.
// ---------------------------------------------------------------------------
__global__ __launch_bounds__(1024)
void prefix_kernel(const int* __restrict__ cnt, int* __restrict__ off)
{
    __shared__ int wsum[16];
    const int tid  = threadIdx.x;          // 0..1023
    const int lane = tid & 63;
    const int wv   = tid >> 6;             // 16 waves
    const int base = tid * 32;

    int local[32];
    int s = 0;
    #pragma unroll
    for (int j = 0; j < 32; ++j) { local[j] = cnt[base + j]; s += local[j]; }

    // inclusive scan of per-thread sums across the wave (64 lanes)
    int x = s;
    #pragma unroll
    for (int d = 1; d < 64; d <<= 1) { int v = __shfl_up(x, d); if (lane >= d) x += v; }
    if (lane == 63) wsum[wv] = x;
    __syncthreads();
    if (wv == 0) {
        int w = (lane < 16) ? wsum[lane] : 0;
        #pragma unroll
        for (int d = 1; d < 16; d <<= 1) { int v = __shfl_up(w, d); if (lane >= d) w += v; }
        if (lane < 16) wsum[lane] = w;     // inclusive wave-sum scan
    }
    __syncthreads();
    const int wbase = (wv == 0) ? 0 : wsum[wv - 1];
    int run = wbase + (x - s);             // exclusive prefix for this thread's chunk
    for (int j = 0; j < 32; ++j) { off[base + j] = run; run += local[j]; }
}

// ---------------------------------------------------------------------------
// Phase 3: scatter 8-byte edge records into dst-sorted order.
// Only |edge_vec| is ever used downstream, so record = { r : f32,
// src(13b) | bucket(15b) : u32 }. Destroys off[] (used as running cursor).
// ---------------------------------------------------------------------------
__global__ __launch_bounds__(256)
void scatter_kernel(const float* __restrict__ edge_vec,
                    const int* __restrict__ edge_src,
                    const int* __restrict__ edge_dst,
                    int* __restrict__ off,
                    uint2* __restrict__ rec)
{
    const long stride = (long)gridDim.x * blockDim.x;
    for (long e = (long)blockIdx.x * blockDim.x + threadIdx.x; e < NEDGES_TOT; e += stride) {
        const int b = (int)(e >> 18);
        const float* ev = edge_vec + e * 3;
        const float vx = ev[0], vy = ev[1], vz = ev[2];
        // self-interaction zeroing in ref is a no-op numerically (r<1e-10 -> r=0)
        const float r = sqrtf(vx * vx + vy * vy + vz * vz);
        const int src    = edge_src[e];
        const int bucket = (b << 13) | edge_dst[e];
        const int pos = atomicAdd(&off[bucket], 1);
        uint2 rc;
        rc.x = __float_as_uint(r);
        rc.y = (unsigned)src | ((unsigned)bucket << 13);
        rec[pos] = rc;
    }
}

// ---------------------------------------------------------------------------
// Phase 4: main MFMA kernel over dst-sorted records.
// GEMM view: msg[e, o] = sum_k Z[e,k] * W2T[k,o],  k = h*32 + i, K = 512
//   Z[e, h*32+i] = rbf_h(e) * x_src[e][i]
// MFMA f32_16x16x32_f16 layouts (HW-verified, learn_hip m89/m91):
//   A: lane holds A[m=lane&15][k_local = (lane>>4)*8 + j], j=0..7
//   B: lane holds B[k_local][n = lane&15]
//   D: lane holds D[row=(lane>>4)*4 + r][col = lane&15], r=0..3
// Sorted input => consecutive D-rows usually share a destination: run-combine
// the 4 rows each lane owns in registers, flush one atomic per run.
// ---------------------------------------------------------------------------
__global__ __launch_bounds__(256, 4)
void pconv_sorted_kernel(const float* __restrict__ features,
                         const float* __restrict__ W,
                         const float* __restrict__ mu,
                         const int* __restrict__ n_norm_p,
                         const uint2* __restrict__ rec,
                         float* __restrict__ out,
                         int num_tiles)   // tiles of 64 records (4 waves x 16)
{
    // W swizzled to exact B-fragment order (conflict-free b128 reads):
    __shared__ _Float16 wsw[16 * 2 * 64 * 8];   // 32 KiB
    __shared__ float mus[16];

    const int tid = threadIdx.x;
    for (int idx = tid; idx < 16384; idx += 256) {
        int j = idx & 7;
        int l = (idx >> 3) & 63;
        int u = (idx >> 9) & 1;
        int s = idx >> 10;
        int n = (l & 15) + (u << 4);          // output channel o
        int i = ((l >> 4) << 3) | j;          // input channel
        wsw[idx] = (_Float16)W[(s * NCOUT + n) * NCIN + i];
    }
    if (tid < 16) mus[tid] = mu[tid];
    __syncthreads();

    const int lane = tid & 63;
    const int wv   = tid >> 6;
    const int m    = lane & 15;   // A-row (record) in main loop; D-col (channel) in epilogue
    const int q    = lane >> 4;

    const int nn = n_norm_p[0];
    const float scale = (nn > 0) ? rsqrtf((float)nn) : 1.0f;

    for (long tile = blockIdx.x; tile < num_tiles; tile += gridDim.x) {
        const long sbase = tile * 64 + (long)wv * 16;   // this wave's 16 records
        const uint2 rc = rec[sbase + m];
        const float r      = __uint_as_float(rc.x);
        const int   src    = (int)(rc.y & 8191u);
        const int   bucket = (int)(rc.y >> 13);         // b*8192 + dst
        const int   b      = bucket >> 13;

        // gather this lane's 8-float slice of x_src (32B-aligned)
        const float* xrow = features + (((long)b << 13) + (long)src) * NCIN + q * 8;
        floatx4 xa = *(const floatx4*)(xrow);
        floatx4 xb = *(const floatx4*)(xrow + 4);

        float rbf[16];
        #pragma unroll
        for (int s = 0; s < 16; ++s) {
            float d = r - mus[s];
            rbf[s] = __expf(-GAMMA * d * d);
        }

        floatx4 accLo = {0.f, 0.f, 0.f, 0.f};   // channels 0..15
        floatx4 accHi = {0.f, 0.f, 0.f, 0.f};   // channels 16..31

        #pragma unroll
        for (int s = 0; s < 16; ++s) {
            const float rb = rbf[s];
            half8 a;
            a[0] = (_Float16)(rb * xa[0]);
            a[1] = (_Float16)(rb * xa[1]);
            a[2] = (_Float16)(rb * xa[2]);
            a[3] = (_Float16)(rb * xa[3]);
            a[4] = (_Float16)(rb * xb[0]);
            a[5] = (_Float16)(rb * xb[1]);
            a[6] = (_Float16)(rb * xb[2]);
            a[7] = (_Float16)(rb * xb[3]);
            half8 b0 = *(const half8*)(wsw + ((s * 2 + 0) * 64 + lane) * 8);
            half8 b1 = *(const half8*)(wsw + ((s * 2 + 1) * 64 + lane) * 8);
            accLo = __builtin_amdgcn_mfma_f32_16x16x32_f16(a, b0, accLo, 0, 0, 0);
            accHi = __builtin_amdgcn_mfma_f32_16x16x32_f16(a, b1, accHi, 0, 0, 0);
        }

        // Epilogue: lane holds D[row = q*4+rr][col = m]. Rows are dst-sorted:
        // run-combine equal-bucket rows in registers, one atomic flush per run.
        int bk[4];
        #pragma unroll
        for (int rr = 0; rr < 4; ++rr) bk[rr] = __shfl(bucket, (q << 2) + rr, 64);

        float sLo = 0.f, sHi = 0.f;
        #pragma unroll
        for (int rr = 0; rr < 4; ++rr) {
            sLo += accLo[rr];
            sHi += accHi[rr];
            const bool flush = (rr == 3) || (bk[rr + 1] != bk[rr]);
            if (flush) {
                float* orow = out + (long)bk[rr] * NCOUT;   // bucket*32 == row in out
                atomicAdd(orow + m,      sLo * scale);
                atomicAdd(orow + m + 16, sHi * scale);
                sLo = 0.f; sHi = 0.f;
            }
        }
    }
}

// ---------------------------------------------------------------------------
// Fallback (previous best, 288 us): direct per-edge atomics, no workspace.
// ---------------------------------------------------------------------------
__global__ __launch_bounds__(256, 4)
void pconv_mfma_kernel(const float* __restrict__ features,
                       const float* __restrict__ edge_vec,
                       const float* __restrict__ W,
                       const float* __restrict__ mu,
                       const int* __restrict__ edge_src,
                       const int* __restrict__ edge_dst,
                       const int* __restrict__ n_norm_p,
                       float* __restrict__ out,
                       int num_tiles)
{
    __shared__ _Float16 wsw[16 * 2 * 64 * 8];
    __shared__ float mus[16];

    const int tid = threadIdx.x;
    for (int idx = tid; idx < 16384; idx += 256) {
        int j = idx & 7;
        int l = (idx >> 3) & 63;
        int u = (idx >> 9) & 1;
        int s = idx >> 10;
        int n = (l & 15) + (u << 4);
        int i = ((l >> 4) << 3) | j;
        wsw[idx] = (_Float16)W[(s * NCOUT + n) * NCIN + i];
    }
    if (tid < 16) mus[tid] = mu[tid];
    __syncthreads();

    const int lane = tid & 63;
    const int wv   = tid >> 6;
    const int m    = lane & 15;
    const int q    = lane >> 4;

    const int nn = n_norm_p[0];
    const float scale = (nn > 0) ? rsqrtf((float)nn) : 1.0f;

    for (long tile = blockIdx.x; tile < num_tiles; tile += gridDim.x) {
        const long ebase = tile * 64 + (long)wv * 16;
        const long ge = ebase + m;
        const int  b  = (int)(ge >> 18);
        const int  src = edge_src[ge];

        const float* xrow = features + (((long)b << 13) + (long)src) * NCIN + q * 8;
        floatx4 xa = *(const floatx4*)(xrow);
        floatx4 xb = *(const floatx4*)(xrow + 4);

        const float* ev = edge_vec + ge * 3;
        float vx = ev[0], vy = ev[1], vz = ev[2];
        float r = sqrtf(vx * vx + vy * vy + vz * vz);

        float rbf[16];
        #pragma unroll
        for (int s = 0; s < 16; ++s) {
            float d = r - mus[s];
            rbf[s] = __expf(-GAMMA * d * d);
        }

        floatx4 accLo = {0.f, 0.f, 0.f, 0.f};
        floatx4 accHi = {0.f, 0.f, 0.f, 0.f};

        #pragma unroll
        for (int s = 0; s < 16; ++s) {
            const float rb = rbf[s];
            half8 a;
            a[0] = (_Float16)(rb * xa[0]);
            a[1] = (_Float16)(rb * xa[1]);
            a[2] = (_Float16)(rb * xa[2]);
            a[3] = (_Float16)(rb * xa[3]);
            a[4] = (_Float16)(rb * xb[0]);
            a[5] = (_Float16)(rb * xb[1]);
            a[6] = (_Float16)(rb * xb[2]);
            a[7] = (_Float16)(rb * xb[3]);
            half8 b0 = *(const half8*)(wsw + ((s * 2 + 0) * 64 + lane) * 8);
            half8 b1 = *(const half8*)(wsw + ((s * 2 + 1) * 64 + lane) * 8);
            accLo = __builtin_amdgcn_mfma_f32_16x16x32_f16(a, b0, accLo, 0, 0, 0);
            accHi = __builtin_amdgcn_mfma_f32_16x16x32_f16(a, b1, accHi, 0, 0, 0);
        }

        #pragma unroll
        for (int rr = 0; rr < 4; ++rr) {
            const long e2  = ebase + q * 4 + rr;
            const int  b2  = (int)(e2 >> 18);
            const int  dst = edge_dst[e2];
            float* orow = out + (((long)b2 << 13) + (long)dst) * NCOUT;
            atomicAdd(orow + m,      accLo[rr] * scale);
            atomicAdd(orow + m + 16, accHi[rr] * scale);
        }
    }
}

extern "C" void kernel_launch(void* const* d_in, const int* in_sizes, int n_in,
                              void* d_out, int out_size, void* d_ws, size_t ws_size,
                              hipStream_t stream) {
    const float* features = (const float*)d_in[0];
    const float* edge_vec = (const float*)d_in[1];
    const float* W        = (const float*)d_in[2];
    const float* mu       = (const float*)d_in[3];
    const int*   edge_src = (const int*)d_in[4];
    const int*   edge_dst = (const int*)d_in[5];
    const int*   n_norm   = (const int*)d_in[6];
    float* out = (float*)d_out;

    // harness poisons d_out with 0xAA before every launch; we accumulate via atomics
    hipMemsetAsync(out, 0, (size_t)out_size * sizeof(float), stream);

    const int num_tiles = NEDGES_TOT / 64;   // 16384 tiles of 64 edges

    // workspace layout: cnt[32768] | off[32768] | rec[1048576] (8 B each)
    const size_t need = (size_t)2 * NBUCKET * sizeof(int) + (size_t)NEDGES_TOT * sizeof(uint2);

    if (d_ws != nullptr && ws_size >= need) {
        char* ws = (char*)d_ws;
        int*   cnt = (int*)ws;
        int*   off = (int*)(ws + (size_t)NBUCKET * sizeof(int));
        uint2* rec = (uint2*)(ws + (size_t)2 * NBUCKET * sizeof(int));

        hipMemsetAsync(cnt, 0, (size_t)NBUCKET * sizeof(int), stream);
        hist_kernel<<<1024, 256, 0, stream>>>(edge_dst, cnt);
        prefix_kernel<<<1, 1024, 0, stream>>>(cnt, off);
        scatter_kernel<<<1024, 256, 0, stream>>>(edge_vec, edge_src, edge_dst, off, rec);
        pconv_sorted_kernel<<<1024, 256, 0, stream>>>(features, W, mu, n_norm,
                                                      rec, out, num_tiles);
    } else {
        // workspace too small: previous best path
        pconv_mfma_kernel<<<1024, 256, 0, stream>>>(features, edge_vec, W, mu,
                                                    edge_src, edge_dst, n_norm,
                                                    out, num_tiles);
    }
}

// Round 2
// 374.972 us; speedup vs baseline: 1.0178x; 1.0178x over previous
//
#include <hip/hip_runtime.h>
#include <cmath>

// Problem constants (from reference)
#define NB 4
#define NP 8192          // 2^13 points per batch
#define NE 262144        // 2^18 edges per batch
#define NCIN 32
#define NCOUT 32
#define NH 16
#define GAMMA 4.0f
#define NBUCKET (NB * NP)        // 32768 destination buckets (b*8192 + dst)
#define NEDGES_TOT (NB * NE)     // 1048576 edges total
#define CAP 96                   // slots per bucket (Poisson(32): P(c>96) ~ 1e-15)
#define GPW 8                    // buckets owned per wave

typedef _Float16 half8 __attribute__((ext_vector_type(8)));
typedef float floatx4 __attribute__((ext_vector_type(4)));

// ---------------------------------------------------------------------------
// Pre-pass (single kernel): bin edges into fixed-capacity per-bucket lists.
// record = { r : f32, src(13b) | bucket(19b… only 15 used) : u32 }
// cnt must be pre-zeroed.
// ---------------------------------------------------------------------------
__global__ __launch_bounds__(256)
void scatter_cap_kernel(const float* __restrict__ edge_vec,
                        const int* __restrict__ edge_src,
                        const int* __restrict__ edge_dst,
                        int* __restrict__ cnt,
                        uint2* __restrict__ rec)
{
    const long stride = (long)gridDim.x * blockDim.x;
    for (long e = (long)blockIdx.x * blockDim.x + threadIdx.x; e < NEDGES_TOT; e += stride) {
        const int b = (int)(e >> 18);                 // NE = 2^18
        const float* ev = edge_vec + e * 3;
        const float vx = ev[0], vy = ev[1], vz = ev[2];
        // self-interaction zeroing in ref is a no-op numerically (r<1e-10 -> r=0)
        const float r = sqrtf(vx * vx + vy * vy + vz * vz);
        const int bucket = (b << 13) | edge_dst[e];
        const int pos = atomicAdd(&cnt[bucket], 1);
        if (pos < CAP) {
            uint2 rc;
            rc.x = __float_as_uint(r);
            rc.y = (unsigned)edge_src[e] | ((unsigned)bucket << 13);
            rec[bucket * CAP + pos] = rc;
        }
    }
}

// ---------------------------------------------------------------------------
// Main kernel: owner-computes. Wave w owns buckets [w*8, w*8+8).
// GEMM view per 16-edge chunk: msg[e,o] = sum_k Z[e,k] * W2T[k,o], K = 512,
//   Z[e, h*32+i] = rbf_h(e) * x_src[e][i]
// MFMA f32_16x16x32_f16 layouts (HW-verified, learn_hip m89/m91):
//   A: lane holds A[m=lane&15][k_local=(lane>>4)*8+j], j=0..7
//   B: lane holds B[k_local][n=lane&15]
//   D: lane holds D[row=(lane>>4)*4+rr][col=m]
// All chunks of a bucket accumulate in the MFMA C registers; at bucket end a
// 2-shuffle cross-q reduce + ONE plain 128-B store per dst row. No atomics,
// no out-memset (every row of out is written exactly once by its owner).
// ---------------------------------------------------------------------------
__global__ __launch_bounds__(256, 4)
void pconv_owner_kernel(const float* __restrict__ features,
                        const float* __restrict__ W,
                        const float* __restrict__ mu,
                        const int* __restrict__ n_norm_p,
                        const int* __restrict__ cnt,
                        const uint2* __restrict__ rec,
                        float* __restrict__ out)
{
    // W swizzled to exact B-fragment order (conflict-free b128 reads):
    //   wsw[ ((s*2+u)*64 + lane)*8 + j ] = W[h=s][o=(lane&15)+16u][i=(lane>>4)*8+j]
    __shared__ _Float16 wsw[16 * 2 * 64 * 8];   // 32 KiB
    __shared__ float mus[16];

    const int tid = threadIdx.x;
    for (int idx = tid; idx < 16384; idx += 256) {
        int j = idx & 7;
        int l = (idx >> 3) & 63;
        int u = (idx >> 9) & 1;
        int s = idx >> 10;
        int n = (l & 15) + (u << 4);          // output channel o
        int i = ((l >> 4) << 3) | j;          // input channel
        wsw[idx] = (_Float16)W[(s * NCOUT + n) * NCIN + i];
    }
    if (tid < 16) mus[tid] = mu[tid];
    __syncthreads();

    const int lane = tid & 63;
    const int wv   = tid >> 6;
    const int m    = lane & 15;   // edge row in chunk; channel in epilogue
    const int q    = lane >> 4;

    const int nn = n_norm_p[0];
    const float scale = (nn > 0) ? rsqrtf((float)nn) : 1.0f;

    const int g0 = (blockIdx.x * 4 + wv) * GPW;   // first bucket of this wave

    // Pack per-bucket counts (<=96: 7 bits) and chunk counts (<=6: 3 bits).
    // Empty buckets get one all-masked chunk so their out rows get zeroed.
    unsigned long long cPack = 0;
    int pcPack = 0, T = 0;
    #pragma unroll
    for (int i = GPW - 1; i >= 0; --i) {
        int ci = cnt[g0 + i];
        if (ci > CAP) ci = CAP;               // overflow clamp (P ~ 1e-15)
        int pci = (ci + 15) >> 4;
        if (pci == 0) pci = 1;
        cPack = (cPack << 7) | (unsigned)ci;
        pcPack = (pcPack << 3) | pci;
        T += pci;
    }

    // wave-uniform walk cursor over (bucket, chunk)
    int rem = pcPack & 7, base = 0, recoff = g0 * CAP, outRow = g0;
    auto advance = [&]() {
        base += 16; rem--;
        if (rem == 0) {
            cPack >>= 7; pcPack >>= 3; rem = pcPack & 7;
            base = 0; recoff += CAP; outRow++;
        }
    };

    // ---- prologue: chunk 0 -> CUR
    int cM = (int)(cPack & 127), baseM = base, outM = outRow;
    bool lastM = (rem == 1);
    uint2 rcN = rec[recoff + base + m];
    advance();

    bool v0 = (baseM + m) < cM;
    float rCur = v0 ? __uint_as_float(rcN.x) : 1e9f;   // masked row -> rbf = 0
    floatx4 xaCur, xbCur;
    {
        int s = (int)(rcN.y & 8191u);
        const float* xr = features + (((outM >> 13) << 13) + s) * NCIN + q * 8;
        xaCur = *(const floatx4*)xr;
        xbCur = *(const floatx4*)(xr + 4);
    }
    bool lastCur = lastM;
    int  outCur  = outM;

    // ---- chunk 1 -> NXT (rec issued, meta saved)
    int cN = 0, baseN = 0, outN = 0;
    bool lastN = false;
    if (T > 1) {
        cN = (int)(cPack & 127); baseN = base; outN = outRow; lastN = (rem == 1);
        rcN = rec[recoff + base + m];
        advance();
    }

    floatx4 accLo = {0.f, 0.f, 0.f, 0.f};
    floatx4 accHi = {0.f, 0.f, 0.f, 0.f};

    for (int t = 0; t < T; ++t) {
        // stage B for chunk t+1: consume its rec, issue its feature gather,
        // then issue rec for chunk t+2. All before this iteration's MFMA, so
        // every load gets ~one full rbf+MFMA phase of flight.
        float rNv = 0.f;
        floatx4 xaN = {0.f,0.f,0.f,0.f}, xbN = {0.f,0.f,0.f,0.f};
        bool lastNv = false; int outNv = 0;
        if (t + 1 < T) {
            bool v = (baseN + m) < cN;
            rNv = v ? __uint_as_float(rcN.x) : 1e9f;
            int s = (int)(rcN.y & 8191u);
            const float* xr = features + (((outN >> 13) << 13) + s) * NCIN + q * 8;
            xaN = *(const floatx4*)xr;
            xbN = *(const floatx4*)(xr + 4);
            lastNv = lastN; outNv = outN;
            if (t + 2 < T) {
                cN = (int)(cPack & 127); baseN = base; outN = outRow; lastN = (rem == 1);
                rcN = rec[recoff + base + m];
                advance();
            }
        }

        // stage C for chunk t
        float rbf[16];
        #pragma unroll
        for (int s = 0; s < 16; ++s) {
            float d = rCur - mus[s];
            rbf[s] = __expf(-GAMMA * d * d);
        }

        #pragma unroll
        for (int s = 0; s < 16; ++s) {
            const float rb = rbf[s];
            half8 a;
            a[0] = (_Float16)(rb * xaCur[0]);
            a[1] = (_Float16)(rb * xaCur[1]);
            a[2] = (_Float16)(rb * xaCur[2]);
            a[3] = (_Float16)(rb * xaCur[3]);
            a[4] = (_Float16)(rb * xbCur[0]);
            a[5] = (_Float16)(rb * xbCur[1]);
            a[6] = (_Float16)(rb * xbCur[2]);
            a[7] = (_Float16)(rb * xbCur[3]);
            half8 b0 = *(const half8*)(wsw + ((s * 2 + 0) * 64 + lane) * 8);
            half8 b1 = *(const half8*)(wsw + ((s * 2 + 1) * 64 + lane) * 8);
            accLo = __builtin_amdgcn_mfma_f32_16x16x32_f16(a, b0, accLo, 0, 0, 0);
            accHi = __builtin_amdgcn_mfma_f32_16x16x32_f16(a, b1, accHi, 0, 0, 0);
        }

        if (lastCur) {
            // reduce 4 rows per lane, then across the 4 q-groups
            float sLo = accLo[0] + accLo[1] + accLo[2] + accLo[3];
            float sHi = accHi[0] + accHi[1] + accHi[2] + accHi[3];
            sLo += __shfl_xor(sLo, 16); sLo += __shfl_xor(sLo, 32);
            sHi += __shfl_xor(sHi, 16); sHi += __shfl_xor(sHi, 32);
            if (q < 2) {
                out[outCur * NCOUT + (q << 4) + m] = ((q == 0) ? sLo : sHi) * scale;
            }
            accLo = (floatx4){0.f, 0.f, 0.f, 0.f};
            accHi = (floatx4){0.f, 0.f, 0.f, 0.f};
        }

        // rotate NXT -> CUR
        rCur = rNv; xaCur = xaN; xbCur = xbN; lastCur = lastNv; outCur = outNv;
    }
}

// ---------------------------------------------------------------------------
// Fallback (no workspace): direct per-edge atomics (the 288 us kernel).
// ---------------------------------------------------------------------------
__global__ __launch_bounds__(256, 4)
void pconv_mfma_kernel(const float* __restrict__ features,
                       const float* __restrict__ edge_vec,
                       const float* __restrict__ W,
                       const float* __restrict__ mu,
                       const int* __restrict__ edge_src,
                       const int* __restrict__ edge_dst,
                       const int* __restrict__ n_norm_p,
                       float* __restrict__ out,
                       int num_tiles)
{
    __shared__ _Float16 wsw[16 * 2 * 64 * 8];
    __shared__ float mus[16];

    const int tid = threadIdx.x;
    for (int idx = tid; idx < 16384; idx += 256) {
        int j = idx & 7;
        int l = (idx >> 3) & 63;
        int u = (idx >> 9) & 1;
        int s = idx >> 10;
        int n = (l & 15) + (u << 4);
        int i = ((l >> 4) << 3) | j;
        wsw[idx] = (_Float16)W[(s * NCOUT + n) * NCIN + i];
    }
    if (tid < 16) mus[tid] = mu[tid];
    __syncthreads();

    const int lane = tid & 63;
    const int wv   = tid >> 6;
    const int m    = lane & 15;
    const int q    = lane >> 4;

    const int nn = n_norm_p[0];
    const float scale = (nn > 0) ? rsqrtf((float)nn) : 1.0f;

    for (long tile = blockIdx.x; tile < num_tiles; tile += gridDim.x) {
        const long ebase = tile * 64 + (long)wv * 16;
        const long ge = ebase + m;
        const int  b  = (int)(ge >> 18);
        const int  src = edge_src[ge];

        const float* xrow = features + (((long)b << 13) + (long)src) * NCIN + q * 8;
        floatx4 xa = *(const floatx4*)(xrow);
        floatx4 xb = *(const floatx4*)(xrow + 4);

        const float* ev = edge_vec + ge * 3;
        float vx = ev[0], vy = ev[1], vz = ev[2];
        float r = sqrtf(vx * vx + vy * vy + vz * vz);

        float rbf[16];
        #pragma unroll
        for (int s = 0; s < 16; ++s) {
            float d = r - mus[s];
            rbf[s] = __expf(-GAMMA * d * d);
        }

        floatx4 accLo = {0.f, 0.f, 0.f, 0.f};
        floatx4 accHi = {0.f, 0.f, 0.f, 0.f};

        #pragma unroll
        for (int s = 0; s < 16; ++s) {
            const float rb = rbf[s];
            half8 a;
            a[0] = (_Float16)(rb * xa[0]);
            a[1] = (_Float16)(rb * xa[1]);
            a[2] = (_Float16)(rb * xa[2]);
            a[3] = (_Float16)(rb * xa[3]);
            a[4] = (_Float16)(rb * xb[0]);
            a[5] = (_Float16)(rb * xb[1]);
            a[6] = (_Float16)(rb * xb[2]);
            a[7] = (_Float16)(rb * xb[3]);
            half8 b0 = *(const half8*)(wsw + ((s * 2 + 0) * 64 + lane) * 8);
            half8 b1 = *(const half8*)(wsw + ((s * 2 + 1) * 64 + lane) * 8);
            accLo = __builtin_amdgcn_mfma_f32_16x16x32_f16(a, b0, accLo, 0, 0, 0);
            accHi = __builtin_amdgcn_mfma_f32_16x16x32_f16(a, b1, accHi, 0, 0, 0);
        }

        #pragma unroll
        for (int rr = 0; rr < 4; ++rr) {
            const long e2  = ebase + q * 4 + rr;
            const int  b2  = (int)(e2 >> 18);
            const int  dst = edge_dst[e2];
            float* orow = out + (((long)b2 << 13) + (long)dst) * NCOUT;
            atomicAdd(orow + m,      accLo[rr] * scale);
            atomicAdd(orow + m + 16, accHi[rr] * scale);
        }
    }
}

extern "C" void kernel_launch(void* const* d_in, const int* in_sizes, int n_in,
                              void* d_out, int out_size, void* d_ws, size_t ws_size,
                              hipStream_t stream) {
    const float* features = (const float*)d_in[0];
    const float* edge_vec = (const float*)d_in[1];
    const float* W        = (const float*)d_in[2];
    const float* mu       = (const float*)d_in[3];
    const int*   edge_src = (const int*)d_in[4];
    const int*   edge_dst = (const int*)d_in[5];
    const int*   n_norm   = (const int*)d_in[6];
    float* out = (float*)d_out;

    // workspace layout: cnt[32768] | rec[32768 * CAP] (8 B each)
    const size_t need = (size_t)NBUCKET * sizeof(int)
                      + (size_t)NBUCKET * CAP * sizeof(uint2);

    if (d_ws != nullptr && ws_size >= need) {
        char* ws = (char*)d_ws;
        int*   cnt = (int*)ws;
        uint2* rec = (uint2*)(ws + (size_t)NBUCKET * sizeof(int));

        hipMemsetAsync(cnt, 0, (size_t)NBUCKET * sizeof(int), stream);
        scatter_cap_kernel<<<2048, 256, 0, stream>>>(edge_vec, edge_src, edge_dst,
                                                     cnt, rec);
        // every out row written exactly once by its owner wave -> no out memset
        pconv_owner_kernel<<<NBUCKET / (4 * GPW), 256, 0, stream>>>(
            features, W, mu, n_norm, cnt, rec, out);
    } else {
        // workspace too small: direct-atomic path (harness poisons out)
        hipMemsetAsync(out, 0, (size_t)out_size * sizeof(float), stream);
        const int num_tiles = NEDGES_TOT / 64;
        pconv_mfma_kernel<<<1024, 256, 0, stream>>>(features, edge_vec, W, mu,
                                                    edge_src, edge_dst, n_norm,
                                                    out, num_tiles);
    }
}

// Round 3
// 270.310 us; speedup vs baseline: 1.4119x; 1.3872x over previous
//
#include <hip/hip_runtime.h>
#include <cmath>

// Problem constants (from reference)
#define NB 4
#define NP 8192          // 2^13 points per batch
#define NE 262144        // 2^18 edges per batch
#define NCIN 32
#define NCOUT 32
#define NH 16
#define GAMMA 4.0f
#define NEDGES_TOT (NB * NE)     // 1048576 edges total
#define TILES_PER_BATCH (NE / 64)  // 4096 tiles of 64 edges per batch

typedef _Float16 half8 __attribute__((ext_vector_type(8)));
typedef float floatx4 __attribute__((ext_vector_type(4)));

// ---------------------------------------------------------------------------
// Single kernel, XCD-sharded by batch.
//
// Why: rocprof rounds 0-2 showed 450-800 MB of HBM FETCH dominated by the
// per-edge feature gather (random 128 B row from a 4 MB table) missing L2 —
// the table thrashes against ~25 MB of streaming edge data in each XCD's
// 4 MB L2, and all 8 XCDs re-fetch the full table. Eliminating atomics
// (round 2) made things WORSE; cutting atomic count 4x (round 1) barely
// moved FETCH. So: keep the simple direct-atomic structure and instead pin
// each batch's 1 MB feature slice to one XCD pair.
//
// Mapping: blocks go round-robin to XCDs (xcd = bid & 7, learn_hip m09).
// Group g = bid & 7 owns batch g>>1; the two groups per batch split tiles
// by parity. Each XCD's L2 then only holds ONE batch's 1 MB feature table
// (re-used ~32x per row) -> gathers become L2 hits.
//
// GEMM view: msg[e, o] = sum_k Z[e,k] * W2T[k,o],  k = h*32 + i, K = 512
//   Z[e, h*32+i] = rbf_h(e) * x_src[e][i]
// MFMA f32_16x16x32_f16 layouts (HW-verified, learn_hip m89/m91):
//   A: lane holds A[m=lane&15][k_local=(lane>>4)*8+j], j=0..7
//   B: lane holds B[k_local][n=lane&15]
//   D: lane holds D[row=(lane>>4)*4+rr][col=m]
// ---------------------------------------------------------------------------
__global__ __launch_bounds__(256, 4)
void pconv_mfma_kernel(const float* __restrict__ features,
                       const float* __restrict__ edge_vec,
                       const float* __restrict__ W,
                       const float* __restrict__ mu,
                       const int* __restrict__ edge_src,
                       const int* __restrict__ edge_dst,
                       const int* __restrict__ n_norm_p,
                       float* __restrict__ out)
{
    // W swizzled to exact B-fragment order (conflict-free b128 reads):
    //   wsw[ ((s*2+u)*64 + lane)*8 + j ] = W[h=s][o=(lane&15)+16u][i=(lane>>4)*8+j]
    __shared__ _Float16 wsw[16 * 2 * 64 * 8];   // 32 KiB
    __shared__ float mus[16];

    const int tid = threadIdx.x;
    for (int idx = tid; idx < 16384; idx += 256) {
        int j = idx & 7;
        int l = (idx >> 3) & 63;
        int u = (idx >> 9) & 1;
        int s = idx >> 10;
        int n = (l & 15) + (u << 4);          // output channel o
        int i = ((l >> 4) << 3) | j;          // input channel
        wsw[idx] = (_Float16)W[(s * NCOUT + n) * NCIN + i];
    }
    if (tid < 16) mus[tid] = mu[tid];
    __syncthreads();

    const int lane = tid & 63;
    const int wv   = tid >> 6;
    const int m    = lane & 15;   // A-row (edge) in main loop; D-col (channel) in epilogue
    const int q    = lane >> 4;

    const int nn = n_norm_p[0];
    const float scale = (nn > 0) ? rsqrtf((float)nn) : 1.0f;

    // XCD-shard: group g = bid&7 -> batch g>>1, tile parity g&1.
    // 128 blocks per group (grid = 1024), 16 tiles each.
    const int g    = blockIdx.x & 7;
    const int bb   = g >> 1;                 // this block's batch (uniform)
    const int sub  = g & 1;
    const int bi   = blockIdx.x >> 3;        // 0..127 within group

    const float* fbase = features + ((long)bb << 13) * NCIN;   // batch feature table
    float* obase = out + ((long)bb << 13) * NCOUT;
    const long ebatch = (long)bb * NE;

    for (int i = bi; i < TILES_PER_BATCH / 2; i += 128) {
        const int  tloc  = (i << 1) + sub;              // tile within batch
        const long ebase = ebatch + (long)tloc * 64 + (long)wv * 16;
        const long ge    = ebase + m;
        const int  src   = edge_src[ge];

        // gather this lane's 8-float slice of x_src (32B-aligned, L2-hot)
        const float* xrow = fbase + (long)src * NCIN + q * 8;
        floatx4 xa = *(const floatx4*)(xrow);
        floatx4 xb = *(const floatx4*)(xrow + 4);

        const float* ev = edge_vec + ge * 3;
        float vx = ev[0], vy = ev[1], vz = ev[2];
        // self-interaction zeroing in ref is a no-op numerically (r<1e-10 -> r=0)
        float r = sqrtf(vx * vx + vy * vy + vz * vz);

        float rbf[16];
        #pragma unroll
        for (int s = 0; s < 16; ++s) {
            float d = r - mus[s];
            rbf[s] = __expf(-GAMMA * d * d);
        }

        floatx4 accLo = {0.f, 0.f, 0.f, 0.f};   // channels 0..15
        floatx4 accHi = {0.f, 0.f, 0.f, 0.f};   // channels 16..31

        #pragma unroll
        for (int s = 0; s < 16; ++s) {
            const float rb = rbf[s];
            half8 a;
            a[0] = (_Float16)(rb * xa[0]);
            a[1] = (_Float16)(rb * xa[1]);
            a[2] = (_Float16)(rb * xa[2]);
            a[3] = (_Float16)(rb * xa[3]);
            a[4] = (_Float16)(rb * xb[0]);
            a[5] = (_Float16)(rb * xb[1]);
            a[6] = (_Float16)(rb * xb[2]);
            a[7] = (_Float16)(rb * xb[3]);
            half8 b0 = *(const half8*)(wsw + ((s * 2 + 0) * 64 + lane) * 8);
            half8 b1 = *(const half8*)(wsw + ((s * 2 + 1) * 64 + lane) * 8);
            accLo = __builtin_amdgcn_mfma_f32_16x16x32_f16(a, b0, accLo, 0, 0, 0);
            accHi = __builtin_amdgcn_mfma_f32_16x16x32_f16(a, b1, accHi, 0, 0, 0);
        }

        // Epilogue: lane holds D[row = q*4+rr][col = m]; row = edge within tile.
        // 16 lanes (same q,rr) cover 16 consecutive channels -> coalesced atomics.
        #pragma unroll
        for (int rr = 0; rr < 4; ++rr) {
            const long e2  = ebase + q * 4 + rr;
            const int  dst = edge_dst[e2];
            float* orow = obase + (long)dst * NCOUT;
            atomicAdd(orow + m,      accLo[rr] * scale);
            atomicAdd(orow + m + 16, accHi[rr] * scale);
        }
    }
}

extern "C" void kernel_launch(void* const* d_in, const int* in_sizes, int n_in,
                              void* d_out, int out_size, void* d_ws, size_t ws_size,
                              hipStream_t stream) {
    const float* features = (const float*)d_in[0];
    const float* edge_vec = (const float*)d_in[1];
    const float* W        = (const float*)d_in[2];
    const float* mu       = (const float*)d_in[3];
    const int*   edge_src = (const int*)d_in[4];
    const int*   edge_dst = (const int*)d_in[5];
    const int*   n_norm   = (const int*)d_in[6];
    float* out = (float*)d_out;

    // harness poisons d_out with 0xAA before every launch; we accumulate via atomics
    hipMemsetAsync(out, 0, (size_t)out_size * sizeof(float), stream);

    // grid MUST be 1024: 8 XCD groups x 128 blocks; 4 blocks/CU (LDS 32KB).
    pconv_mfma_kernel<<<1024, 256, 0, stream>>>(features, edge_vec, W, mu,
                                                edge_src, edge_dst, n_norm, out);
}